// Round 5
// baseline (152.678 us; speedup 1.0000x reference)
//
#include <hip/hip_runtime.h>
#include <hip/hip_bf16.h>

#define B_DIM 16
#define T_DIM 2048
#define NI 128
#define NO 64
#define TCHUNK 64
#define NCHUNK (T_DIM / TCHUNK)   // 32 chunks -> 512 blocks

typedef __attribute__((ext_vector_type(8))) short short8;
typedef __attribute__((ext_vector_type(4))) float floatx4;

// XOR bank swizzle on 16B slot index: reads (slot = 64-aligned base + lane) get a
// wave-uniform XOR -> still conflict-free; scattered writes spread across bank groups.
#define SW(s) ((s) ^ (((s) >> 6) & 7))

__device__ __forceinline__ unsigned short f2bf(float f) {
    union { float f; unsigned int u; } v; v.f = f;
    unsigned int u = v.u;
    return (unsigned short)((u + 0x7FFFu + ((u >> 16) & 1u)) >> 16);  // RNE
}
__device__ __forceinline__ float bf2f(unsigned short h) {
    union { unsigned int u; float f; } v; v.u = ((unsigned int)h) << 16; return v.f;
}

// Single fused kernel: distances -> softmax -> E^T partials -> flag -> spin ->
// distributed cross-chunk reduce. grid = 512 blocks x 256 thr, 2 blocks/CU.
__global__ __launch_bounds__(256, 2) void lde_fused(
    const float* __restrict__ x,          // (B,T,NI)
    const float* __restrict__ s,          // (NO)
    const float* __restrict__ m,          // (NI,NO)
    unsigned short* __restrict__ part_e,  // ws: (B*NCHUNK, 8192) bf16, lane-sequential
    float* __restrict__ part_w1,          // ws: (B*NCHUNK, NO)
    unsigned int* __restrict__ flags,     // ws: (B*NCHUNK) poisoned 0xAAAAAAAA each launch
    float* __restrict__ out)              // (B,NO,NI)
{
    __shared__ unsigned short x_frag [4 * 4 * 64 * 8]; // A of GEMM1: x[t][i], 16KB
    __shared__ unsigned short xT_frag[8 * 2 * 64 * 8]; // A of GEMM2 (E^T): x keyed by i, 16KB
    __shared__ unsigned short m_frag [4 * 4 * 64 * 8]; // B of GEMM1: m keyed by o, 16KB
    __shared__ unsigned short wT_frag[4 * 2 * 64 * 8]; // B of GEMM2: w keyed by o, 8KB
    __shared__ float xxc[TCHUNK];
    __shared__ float mm_s[NO];
    __shared__ float w1w[4 * NO];

    const int tid   = threadIdx.x;
    const int b     = blockIdx.x >> 5;       // / NCHUNK
    const int chunk = blockIdx.x & (NCHUNK - 1);
    const int t0    = chunk * TCHUNK;

    if (tid < NO) mm_s[tid] = 0.f;
    __syncthreads();

    // ---- stage x chunk: thread = (tb = tid>>4 -> 4 t-rows, ib = tid&15 -> 8 i-cols)
    {
        const int tb = tid >> 4;
        const int ib = tid & 15;
        const float* xg = x + ((size_t)b * T_DIM + t0 + tb * 4) * NI + ib * 8;
        unsigned short h[4][8];
        float ss4[4];
        #pragma unroll
        for (int r = 0; r < 4; ++r) {
            float4 v0 = reinterpret_cast<const float4*>(xg + (size_t)r * NI)[0];
            float4 v1 = reinterpret_cast<const float4*>(xg + (size_t)r * NI)[1];
            ss4[r] = v0.x*v0.x + v0.y*v0.y + v0.z*v0.z + v0.w*v0.w
                   + v1.x*v1.x + v1.y*v1.y + v1.z*v1.z + v1.w*v1.w;
            h[r][0] = f2bf(v0.x); h[r][1] = f2bf(v0.y); h[r][2] = f2bf(v0.z); h[r][3] = f2bf(v0.w);
            h[r][4] = f2bf(v1.x); h[r][5] = f2bf(v1.y); h[r][6] = f2bf(v1.z); h[r][7] = f2bf(v1.w);
        }
        const int ttile = tb >> 2;
        #pragma unroll
        for (int r = 0; r < 4; ++r) {
            const int tm = (tb & 3) * 4 + r;
            const int slot = (ttile * 4 + (ib >> 2)) * 64 + tm + 16 * (ib & 3);
            *reinterpret_cast<short8*>(&x_frag[SW(slot) * 8]) =
                *reinterpret_cast<const short8*>(h[r]);
        }
        const int itile = ib >> 1;
        const int ksT = tb >> 3;
        const int qT  = (tb >> 1) & 3;
        const int j0T = (tb & 1) * 4;
        #pragma unroll
        for (int ii = 0; ii < 8; ++ii) {
            const int slot = (itile * 2 + ksT) * 64 + (ib & 1) * 8 + ii + 16 * qT;
            ushort4 v; v.x = h[0][ii]; v.y = h[1][ii]; v.z = h[2][ii]; v.w = h[3][ii];
            *reinterpret_cast<ushort4*>(&xT_frag[SW(slot) * 8 + j0T]) = v;
        }
        #pragma unroll
        for (int r = 0; r < 4; ++r) {
            float sv_ = ss4[r];
            #pragma unroll
            for (int off = 1; off < 16; off <<= 1) sv_ += __shfl_xor(sv_, off, 64);
            if (ib == 0) xxc[tb * 4 + r] = sv_;
        }
    }

    // ---- stage m: thread = (o2 = tid&31 -> o pair, ibm = tid>>5 -> 16 i rows)
    {
        const int o2  = tid & 31;
        const int ibm = tid >> 5;
        const int o0  = o2 * 2;
        const int otile = o2 >> 3;
        const int om0   = (o2 & 7) * 2;
        float mm0 = 0.f, mm1 = 0.f;
        #pragma unroll
        for (int p = 0; p < 8; ++p) {
            const int i = ibm * 16 + p * 2;
            float2 va = *reinterpret_cast<const float2*>(m + (size_t)i * NO + o0);
            float2 vb = *reinterpret_cast<const float2*>(m + (size_t)(i + 1) * NO + o0);
            mm0 += va.x * va.x + vb.x * vb.x;
            mm1 += va.y * va.y + vb.y * vb.y;
            const int ks = i >> 5, q = (i & 31) >> 3, j = i & 7;
            const int slotbase = (otile * 4 + ks) * 64 + 16 * q;
            ushort2 wa; wa.x = f2bf(va.x); wa.y = f2bf(vb.x);
            ushort2 wbv; wbv.x = f2bf(va.y); wbv.y = f2bf(vb.y);
            *reinterpret_cast<ushort2*>(&m_frag[SW(slotbase + om0)     * 8 + j]) = wa;
            *reinterpret_cast<ushort2*>(&m_frag[SW(slotbase + om0 + 1) * 8 + j]) = wbv;
        }
        atomicAdd(&mm_s[o0], mm0);
        atomicAdd(&mm_s[o0 + 1], mm1);
    }
    __syncthreads();

    const int wv   = tid >> 6;
    const int lane = tid & 63;
    const int quad = lane >> 4, c = lane & 15;

    // ---- GEMM1: S[t][o] = sum_i x[t][i]*m[i][o].
    floatx4 zero = {0.f, 0.f, 0.f, 0.f};
    floatx4 acc[4];
    #pragma unroll
    for (int ot = 0; ot < 4; ++ot) acc[ot] = zero;
    #pragma unroll
    for (int ks = 0; ks < 4; ++ks) {
        short8 a = *reinterpret_cast<const short8*>(&x_frag[SW((wv * 4 + ks) * 64 + lane) * 8]);
        #pragma unroll
        for (int ot = 0; ot < 4; ++ot) {
            short8 bb = *reinterpret_cast<const short8*>(&m_frag[SW((ot * 4 + ks) * 64 + lane) * 8]);
            acc[ot] = __builtin_amdgcn_mfma_f32_16x16x32_bf16(a, bb, acc[ot], 0, 0, 0);
        }
    }

    // ---- softmax over o
    float sv[4], mv[4];
    #pragma unroll
    for (int ot = 0; ot < 4; ++ot) { sv[ot] = s[16 * ot + c]; mv[ot] = mm_s[16 * ot + c]; }
    floatx4 xxq = *reinterpret_cast<const floatx4*>(&xxc[wv * 16 + quad * 4]);

    float w[4][4];
    #pragma unroll
    for (int r = 0; r < 4; ++r) {
        float mx = -1e30f;
        #pragma unroll
        for (int ot = 0; ot < 4; ++ot) {
            float d = sv[ot] * (xxq[r] - 2.f * acc[ot][r] + mv[ot]);
            w[ot][r] = d;
            mx = fmaxf(mx, d);
        }
        #pragma unroll
        for (int off = 1; off < 16; off <<= 1) mx = fmaxf(mx, __shfl_xor(mx, off, 64));
        float sum = 0.f;
        #pragma unroll
        for (int ot = 0; ot < 4; ++ot) { float e = __expf(w[ot][r] - mx); w[ot][r] = e; sum += e; }
        #pragma unroll
        for (int off = 1; off < 16; off <<= 1) sum += __shfl_xor(sum, off, 64);
        const float inv = 1.f / sum;
        #pragma unroll
        for (int ot = 0; ot < 4; ++ot) w[ot][r] *= inv;
    }

    // ---- W1 per-wave partial
    #pragma unroll
    for (int ot = 0; ot < 4; ++ot) {
        float lsum = w[ot][0] + w[ot][1] + w[ot][2] + w[ot][3];
        lsum += __shfl_xor(lsum, 16, 64);
        lsum += __shfl_xor(lsum, 32, 64);
        if (quad == 0) w1w[wv * 64 + 16 * ot + c] = lsum;
    }

    // ---- write w to wT_frag (B of GEMM2)
    {
        const int ksw = wv >> 1;
        const int qd  = (wv & 1) * 2 + (quad >> 1);
        const int j0  = (quad & 1) * 4;
        #pragma unroll
        for (int ot = 0; ot < 4; ++ot) {
            const int slot = (ot * 2 + ksw) * 64 + c + 16 * qd;
            ushort4 v;
            v.x = f2bf(w[ot][0]); v.y = f2bf(w[ot][1]);
            v.z = f2bf(w[ot][2]); v.w = f2bf(w[ot][3]);
            *reinterpret_cast<ushort4*>(&wT_frag[SW(slot) * 8 + j0]) = v;
        }
    }
    __syncthreads();

    // ---- GEMM2 (E^T): Et[i][o] = sum_t x[t][i]*w[t][o]
    floatx4 acc2[2][4];
    #pragma unroll
    for (int it2 = 0; it2 < 2; ++it2)
        #pragma unroll
        for (int ot = 0; ot < 4; ++ot) acc2[it2][ot] = zero;
    #pragma unroll
    for (int ks = 0; ks < 2; ++ks) {
        short8 a0 = *reinterpret_cast<const short8*>(&xT_frag[SW(((2 * wv + 0) * 2 + ks) * 64 + lane) * 8]);
        short8 a1 = *reinterpret_cast<const short8*>(&xT_frag[SW(((2 * wv + 1) * 2 + ks) * 64 + lane) * 8]);
        #pragma unroll
        for (int ot = 0; ot < 4; ++ot) {
            short8 bb = *reinterpret_cast<const short8*>(&wT_frag[SW((ot * 2 + ks) * 64 + lane) * 8]);
            acc2[0][ot] = __builtin_amdgcn_mfma_f32_16x16x32_bf16(a0, bb, acc2[0][ot], 0, 0, 0);
            acc2[1][ot] = __builtin_amdgcn_mfma_f32_16x16x32_bf16(a1, bb, acc2[1][ot], 0, 0, 0);
        }
    }

    // ---- store bf16 partials, lane-sequential
    unsigned short* pe = part_e + (size_t)blockIdx.x * (NO * NI);
    #pragma unroll
    for (int it2 = 0; it2 < 2; ++it2)
        #pragma unroll
        for (int ot = 0; ot < 4; ++ot) {
            ushort4 h;
            h.x = f2bf(acc2[it2][ot][0]); h.y = f2bf(acc2[it2][ot][1]);
            h.z = f2bf(acc2[it2][ot][2]); h.w = f2bf(acc2[it2][ot][3]);
            *reinterpret_cast<ushort4*>(&pe[(((it2 * 4 + ot) * 256) + tid) * 4]) = h;
        }
    if (tid < NO)
        part_w1[blockIdx.x * NO + tid] =
            w1w[tid] + w1w[64 + tid] + w1w[128 + tid] + w1w[192 + tid];

    // ---- release: make partials visible device-wide, then raise our flag
    __threadfence();
    __syncthreads();
    if (tid == 0) atomicExch(&flags[blockIdx.x], 1u);

    // ---- acquire: wait for all 32 chunks of this batch (threads 0..31 poll)
    if (tid < NCHUNK) {
        while (__hip_atomic_load(&flags[b * NCHUNK + tid], __ATOMIC_RELAXED,
                                 __HIP_MEMORY_SCOPE_AGENT) != 1u) { }
    }
    __syncthreads();
    __threadfence();   // invalidate stale caches before reading other blocks' partials

    // ---- distributed reduce: this block reduces slice `chunk` of batch b's output.
    // slot-index bits: [10:8]=k, [7:6]=wvr, [5:4]=quadr, [3:0]=cr  (4 floats per slot)
    if (tid < 64) {
        const int k    = (chunk >> 2) & 7;
        const int ot   = k & 3, it2 = k >> 2;
        const int wvr  = chunk & 3;
        const int quadr = tid >> 4;
        const int cr    = tid & 15;
        const int o    = ot * 16 + cr;
        const int i0   = (2 * wvr + it2) * 16 + quadr * 4;
        const int within = (chunk << 6) + tid;

        float w1v = 0.f;
        const float* pw = part_w1 + (size_t)b * NCHUNK * NO + o;
        #pragma unroll
        for (int j = 0; j < 8; ++j) w1v += pw[(quadr * 8 + j) * NO];
        w1v += __shfl_xor(w1v, 16, 64);
        w1v += __shfl_xor(w1v, 32, 64);

        float a0 = 0.f, a1 = 0.f, a2 = 0.f, a3 = 0.f;
        const unsigned short* pp = part_e + (size_t)b * NCHUNK * (NO * NI) + (size_t)within * 4;
        #pragma unroll
        for (int cc = 0; cc < NCHUNK; ++cc) {
            ushort4 v = *reinterpret_cast<const ushort4*>(pp + (size_t)cc * (NO * NI));
            a0 += bf2f(v.x); a1 += bf2f(v.y); a2 += bf2f(v.z); a3 += bf2f(v.w);
        }

        const float inv = 1.f / (float)T_DIM;
        float4 r;
        r.x = (a0 - w1v * m[(i0 + 0) * NO + o]) * inv;
        r.y = (a1 - w1v * m[(i0 + 1) * NO + o]) * inv;
        r.z = (a2 - w1v * m[(i0 + 2) * NO + o]) * inv;
        r.w = (a3 - w1v * m[(i0 + 3) * NO + o]) * inv;
        *reinterpret_cast<float4*>(&out[((size_t)b * NO + o) * NI + i0]) = r;
    }
}

extern "C" void kernel_launch(void* const* d_in, const int* in_sizes, int n_in,
                              void* d_out, int out_size, void* d_ws, size_t ws_size,
                              hipStream_t stream) {
    const float* x = (const float*)d_in[0];
    const float* s = (const float*)d_in[1];
    const float* m = (const float*)d_in[2];
    float* out = (float*)d_out;                                   // B*NO*NI floats
    unsigned short* part_e = (unsigned short*)d_ws;               // 512*8192 bf16 = 8.4 MB
    float* part_w1 = (float*)(part_e + (size_t)B_DIM * NCHUNK * NO * NI);  // 512*64 floats
    unsigned int* flags = (unsigned int*)(part_w1 + (size_t)B_DIM * NCHUNK * NO); // 512 uints
    // flags need no init: harness poisons ws to 0xAA (0xAAAAAAAA != 1) before every launch.

    lde_fused<<<dim3(B_DIM * NCHUNK), dim3(256), 0, stream>>>(
        x, s, m, part_e, part_w1, flags, out);
}

// Round 6
// 74.706 us; speedup vs baseline: 2.0437x; 2.0437x over previous
//
#include <hip/hip_runtime.h>
#include <hip/hip_bf16.h>

#define B_DIM 16
#define T_DIM 2048
#define NI 128
#define NO 64
#define TCHUNK 128
#define NSUB 2                    // 2 x 64-t sub-chunks per block
#define NCHUNK (T_DIM / TCHUNK)   // 16 chunks -> 256 main blocks

typedef __attribute__((ext_vector_type(8))) short short8;
typedef __attribute__((ext_vector_type(4))) float floatx4;

// XOR bank swizzle on 16B slot index: reads (slot = 64-aligned base + lane) get a
// wave-uniform XOR -> still conflict-free; scattered writes spread across bank groups.
#define SW(s) ((s) ^ (((s) >> 6) & 7))

__device__ __forceinline__ unsigned short f2bf(float f) {
    union { float f; unsigned int u; } v; v.f = f;
    unsigned int u = v.u;
    return (unsigned short)((u + 0x7FFFu + ((u >> 16) & 1u)) >> 16);  // RNE
}
__device__ __forceinline__ float bf2f(unsigned short h) {
    union { unsigned int u; float f; } v; v.u = ((unsigned int)h) << 16; return v.f;
}

// Main fused kernel: distances -> softmax -> E^T partials (bf16, lane-sequential).
// grid = B_DIM * NCHUNK = 256 blocks of 256 threads, each handling 128 t-rows
// as two 64-t sub-chunks through the same LDS buffers. 2 blocks/CU (~58KB LDS).
__global__ __launch_bounds__(256, 2) void lde_main(
    const float* __restrict__ x,          // (B,T,NI)
    const float* __restrict__ s,          // (NO)
    const float* __restrict__ m,          // (NI,NO)
    unsigned short* __restrict__ part_e,  // (B*NCHUNK, 8192) bf16, lane-sequential order
    float* __restrict__ part_w1)          // (B*NCHUNK, NO)
{
    __shared__ unsigned short x_frag [4 * 4 * 64 * 8]; // A of GEMM1: x[t][i], 16KB
    __shared__ unsigned short xT_frag[8 * 2 * 64 * 8]; // A of GEMM2 (E^T): x keyed by i, 16KB
    __shared__ unsigned short m_frag [4 * 4 * 64 * 8]; // B of GEMM1: m keyed by o, 16KB
    __shared__ unsigned short wT_frag[4 * 2 * 64 * 8]; // B of GEMM2: w keyed by o, 8KB
    __shared__ float xxc[64];
    __shared__ float mm_s[NO];
    __shared__ float w1w[4 * NO];

    const int tid   = threadIdx.x;
    const int b     = blockIdx.x >> 4;               // / NCHUNK
    const int chunk = blockIdx.x & (NCHUNK - 1);

    if (tid < NO) mm_s[tid] = 0.f;
    w1w[tid] = 0.f;
    __syncthreads();

    // ---- stage m once: thread = (o2 = tid&31 -> o pair, ibm = tid>>5 -> 16 i rows)
    {
        const int o2  = tid & 31;
        const int ibm = tid >> 5;
        const int o0  = o2 * 2;
        const int otile = o2 >> 3;
        const int om0   = (o2 & 7) * 2;
        float mm0 = 0.f, mm1 = 0.f;
        #pragma unroll
        for (int p = 0; p < 8; ++p) {
            const int i = ibm * 16 + p * 2;
            float2 va = *reinterpret_cast<const float2*>(m + (size_t)i * NO + o0);
            float2 vb = *reinterpret_cast<const float2*>(m + (size_t)(i + 1) * NO + o0);
            mm0 += va.x * va.x + vb.x * vb.x;
            mm1 += va.y * va.y + vb.y * vb.y;
            const int ks = i >> 5, q = (i & 31) >> 3, j = i & 7;
            const int slotbase = (otile * 4 + ks) * 64 + 16 * q;
            ushort2 wa; wa.x = f2bf(va.x); wa.y = f2bf(vb.x);
            ushort2 wbv; wbv.x = f2bf(va.y); wbv.y = f2bf(vb.y);
            *reinterpret_cast<ushort2*>(&m_frag[SW(slotbase + om0)     * 8 + j]) = wa;
            *reinterpret_cast<ushort2*>(&m_frag[SW(slotbase + om0 + 1) * 8 + j]) = wbv;
        }
        atomicAdd(&mm_s[o0], mm0);
        atomicAdd(&mm_s[o0 + 1], mm1);
    }

    const int wv   = tid >> 6;
    const int lane = tid & 63;
    const int quad = lane >> 4, c = lane & 15;

    floatx4 zero = {0.f, 0.f, 0.f, 0.f};
    floatx4 acc2[2][4];                  // GEMM2 accumulator, carried across sub-chunks
    #pragma unroll
    for (int it2 = 0; it2 < 2; ++it2)
        #pragma unroll
        for (int ot = 0; ot < 4; ++ot) acc2[it2][ot] = zero;

    for (int sc = 0; sc < NSUB; ++sc) {
        if (sc > 0) __syncthreads();     // all waves done with GEMM2 before restaging
        const int t0 = chunk * TCHUNK + sc * 64;

        // ---- stage x sub-chunk: thread = (tb = tid>>4 -> 4 t-rows, ib = tid&15 -> 8 i-cols)
        {
            const int tb = tid >> 4;
            const int ib = tid & 15;
            const float* xg = x + ((size_t)b * T_DIM + t0 + tb * 4) * NI + ib * 8;
            unsigned short h[4][8];
            float ss4[4];
            #pragma unroll
            for (int r = 0; r < 4; ++r) {
                float4 v0 = reinterpret_cast<const float4*>(xg + (size_t)r * NI)[0];
                float4 v1 = reinterpret_cast<const float4*>(xg + (size_t)r * NI)[1];
                ss4[r] = v0.x*v0.x + v0.y*v0.y + v0.z*v0.z + v0.w*v0.w
                       + v1.x*v1.x + v1.y*v1.y + v1.z*v1.z + v1.w*v1.w;
                h[r][0] = f2bf(v0.x); h[r][1] = f2bf(v0.y); h[r][2] = f2bf(v0.z); h[r][3] = f2bf(v0.w);
                h[r][4] = f2bf(v1.x); h[r][5] = f2bf(v1.y); h[r][6] = f2bf(v1.z); h[r][7] = f2bf(v1.w);
            }
            const int ttile = tb >> 2;
            #pragma unroll
            for (int r = 0; r < 4; ++r) {
                const int tm = (tb & 3) * 4 + r;
                const int slot = (ttile * 4 + (ib >> 2)) * 64 + tm + 16 * (ib & 3);
                *reinterpret_cast<short8*>(&x_frag[SW(slot) * 8]) =
                    *reinterpret_cast<const short8*>(h[r]);
            }
            const int itile = ib >> 1;
            const int ksT = tb >> 3;
            const int qT  = (tb >> 1) & 3;
            const int j0T = (tb & 1) * 4;
            #pragma unroll
            for (int ii = 0; ii < 8; ++ii) {
                const int slot = (itile * 2 + ksT) * 64 + (ib & 1) * 8 + ii + 16 * qT;
                ushort4 v; v.x = h[0][ii]; v.y = h[1][ii]; v.z = h[2][ii]; v.w = h[3][ii];
                *reinterpret_cast<ushort4*>(&xT_frag[SW(slot) * 8 + j0T]) = v;
            }
            #pragma unroll
            for (int r = 0; r < 4; ++r) {
                float sv_ = ss4[r];
                #pragma unroll
                for (int off = 1; off < 16; off <<= 1) sv_ += __shfl_xor(sv_, off, 64);
                if (ib == 0) xxc[tb * 4 + r] = sv_;
            }
        }
        __syncthreads();

        // ---- GEMM1: S[t][o] = sum_i x[t][i]*m[i][o]
        floatx4 acc[4];
        #pragma unroll
        for (int ot = 0; ot < 4; ++ot) acc[ot] = zero;
        #pragma unroll
        for (int ks = 0; ks < 4; ++ks) {
            short8 a = *reinterpret_cast<const short8*>(&x_frag[SW((wv * 4 + ks) * 64 + lane) * 8]);
            #pragma unroll
            for (int ot = 0; ot < 4; ++ot) {
                short8 bb = *reinterpret_cast<const short8*>(&m_frag[SW((ot * 4 + ks) * 64 + lane) * 8]);
                acc[ot] = __builtin_amdgcn_mfma_f32_16x16x32_bf16(a, bb, acc[ot], 0, 0, 0);
            }
        }

        // ---- softmax over o
        float sv[4], mv[4];
        #pragma unroll
        for (int ot = 0; ot < 4; ++ot) { sv[ot] = s[16 * ot + c]; mv[ot] = mm_s[16 * ot + c]; }
        floatx4 xxq = *reinterpret_cast<const floatx4*>(&xxc[wv * 16 + quad * 4]);

        float w[4][4];
        #pragma unroll
        for (int r = 0; r < 4; ++r) {
            float mx = -1e30f;
            #pragma unroll
            for (int ot = 0; ot < 4; ++ot) {
                float d = sv[ot] * (xxq[r] - 2.f * acc[ot][r] + mv[ot]);
                w[ot][r] = d;
                mx = fmaxf(mx, d);
            }
            #pragma unroll
            for (int off = 1; off < 16; off <<= 1) mx = fmaxf(mx, __shfl_xor(mx, off, 64));
            float sum = 0.f;
            #pragma unroll
            for (int ot = 0; ot < 4; ++ot) { float e = __expf(w[ot][r] - mx); w[ot][r] = e; sum += e; }
            #pragma unroll
            for (int off = 1; off < 16; off <<= 1) sum += __shfl_xor(sum, off, 64);
            const float inv = 1.f / sum;
            #pragma unroll
            for (int ot = 0; ot < 4; ++ot) w[ot][r] *= inv;
        }

        // ---- W1 per-wave accumulate (single writer per slot; read only after later barriers)
        #pragma unroll
        for (int ot = 0; ot < 4; ++ot) {
            float lsum = w[ot][0] + w[ot][1] + w[ot][2] + w[ot][3];
            lsum += __shfl_xor(lsum, 16, 64);
            lsum += __shfl_xor(lsum, 32, 64);
            if (quad == 0) w1w[wv * 64 + 16 * ot + c] += lsum;
        }

        // ---- write w to wT_frag (B of GEMM2)
        {
            const int ksw = wv >> 1;
            const int qd  = (wv & 1) * 2 + (quad >> 1);
            const int j0  = (quad & 1) * 4;
            #pragma unroll
            for (int ot = 0; ot < 4; ++ot) {
                const int slot = (ot * 2 + ksw) * 64 + c + 16 * qd;
                ushort4 v;
                v.x = f2bf(w[ot][0]); v.y = f2bf(w[ot][1]);
                v.z = f2bf(w[ot][2]); v.w = f2bf(w[ot][3]);
                *reinterpret_cast<ushort4*>(&wT_frag[SW(slot) * 8 + j0]) = v;
            }
        }
        __syncthreads();

        // ---- GEMM2 (E^T): Et[i][o] += sum_t x[t][i]*w[t][o]
        #pragma unroll
        for (int ks = 0; ks < 2; ++ks) {
            short8 a0 = *reinterpret_cast<const short8*>(&xT_frag[SW(((2 * wv + 0) * 2 + ks) * 64 + lane) * 8]);
            short8 a1 = *reinterpret_cast<const short8*>(&xT_frag[SW(((2 * wv + 1) * 2 + ks) * 64 + lane) * 8]);
            #pragma unroll
            for (int ot = 0; ot < 4; ++ot) {
                short8 bb = *reinterpret_cast<const short8*>(&wT_frag[SW((ot * 2 + ks) * 64 + lane) * 8]);
                acc2[0][ot] = __builtin_amdgcn_mfma_f32_16x16x32_bf16(a0, bb, acc2[0][ot], 0, 0, 0);
                acc2[1][ot] = __builtin_amdgcn_mfma_f32_16x16x32_bf16(a1, bb, acc2[1][ot], 0, 0, 0);
            }
        }
    }

    // ---- store bf16 partials, lane-sequential: slot = (it2*4+ot)*256 + tid, 4 shorts each.
    unsigned short* pe = part_e + (size_t)blockIdx.x * (NO * NI);
    #pragma unroll
    for (int it2 = 0; it2 < 2; ++it2)
        #pragma unroll
        for (int ot = 0; ot < 4; ++ot) {
            ushort4 h;
            h.x = f2bf(acc2[it2][ot][0]); h.y = f2bf(acc2[it2][ot][1]);
            h.z = f2bf(acc2[it2][ot][2]); h.w = f2bf(acc2[it2][ot][3]);
            *reinterpret_cast<ushort4*>(&pe[(((it2 * 4 + ot) * 256) + tid) * 4]) = h;
        }
    // w1w last written before the pre-GEMM2 barrier of the last sub-chunk -> safe to read.
    if (tid < NO)
        part_w1[blockIdx.x * NO + tid] =
            w1w[tid] + w1w[64 + tid] + w1w[128 + tid] + w1w[192 + tid];
}

// Reduce: 512 blocks x 64 threads; each lane owns one float4 of out.
// Reads partials in the exact lane-sequential order they were stored.
__global__ __launch_bounds__(64) void lde_reduce(
    const unsigned short* __restrict__ part_e,  // (B*NCHUNK, 8192)
    const float* __restrict__ part_w1,          // (B*NCHUNK, NO)
    const float* __restrict__ m,                // (NI,NO)
    float* __restrict__ out)                    // (B,NO,NI)
{
    const int tid = threadIdx.x;                 // 0..63
    const int blk = blockIdx.x;                  // 0..511
    const int b      = blk >> 5;
    const int within = ((blk & 31) << 6) + tid;  // 0..2047 (slot index, 4 floats/slot)
    const int k    = (blk >> 2) & 7;             // = it2*4 + ot (block-uniform)
    const int ot   = k & 3, it2 = k >> 2;
    const int wvr  = blk & 3;
    const int quad = tid >> 4;
    const int c    = tid & 15;
    const int o    = ot * 16 + c;
    const int i0   = (2 * wvr + it2) * 16 + quad * 4;

    // w1[b,o]: lane sums 4 chunks, butterfly over quads (16 chunks total)
    float w1v = 0.f;
    const float* pw = part_w1 + (size_t)b * NCHUNK * NO + o;
    #pragma unroll
    for (int j = 0; j < 4; ++j) w1v += pw[(quad * 4 + j) * NO];
    w1v += __shfl_xor(w1v, 16, 64);
    w1v += __shfl_xor(w1v, 32, 64);

    // sum bf16 partials over 16 chunks (fp32 accumulate)
    float a0 = 0.f, a1 = 0.f, a2 = 0.f, a3 = 0.f;
    const unsigned short* pp = part_e + (size_t)b * NCHUNK * (NO * NI) + (size_t)within * 4;
    #pragma unroll
    for (int cc = 0; cc < NCHUNK; ++cc) {
        ushort4 v = *reinterpret_cast<const ushort4*>(pp + (size_t)cc * (NO * NI));
        a0 += bf2f(v.x); a1 += bf2f(v.y); a2 += bf2f(v.z); a3 += bf2f(v.w);
    }

    const float inv = 1.f / (float)T_DIM;
    float4 r;
    r.x = (a0 - w1v * m[(i0 + 0) * NO + o]) * inv;
    r.y = (a1 - w1v * m[(i0 + 1) * NO + o]) * inv;
    r.z = (a2 - w1v * m[(i0 + 2) * NO + o]) * inv;
    r.w = (a3 - w1v * m[(i0 + 3) * NO + o]) * inv;
    *reinterpret_cast<float4*>(&out[((size_t)b * NO + o) * NI + i0]) = r;
}

extern "C" void kernel_launch(void* const* d_in, const int* in_sizes, int n_in,
                              void* d_out, int out_size, void* d_ws, size_t ws_size,
                              hipStream_t stream) {
    const float* x = (const float*)d_in[0];
    const float* s = (const float*)d_in[1];
    const float* m = (const float*)d_in[2];
    float* out = (float*)d_out;                                   // B*NO*NI floats
    unsigned short* part_e = (unsigned short*)d_ws;               // 256*8192 bf16 = 4.2 MB
    float* part_w1 = (float*)(part_e + (size_t)B_DIM * NCHUNK * NO * NI);  // 256*64 floats

    lde_main<<<dim3(B_DIM * NCHUNK), dim3(256), 0, stream>>>(x, s, m, part_e, part_w1);
    lde_reduce<<<dim3(512), dim3(64), 0, stream>>>(part_e, part_w1, m, out);
}